// Round 1
// baseline (245.390 us; speedup 1.0000x reference)
//
#include <hip/hip_runtime.h>

// MultiscaleLLN: out = x / (gauss13x13(lum(x)) / dens + eps), 4 pyramid levels.
// Separable Gaussian; dens analytic via prefix sums. R3: fix 2-px row-conv
// offset. R4: XCD-aware block swizzle — consecutive logical tiles (which share
// 80x28 halo lines) were round-robined across the 8 non-coherent XCD L2s,
// re-fetching ~65 MB of halo from HBM. Swizzle gives each XCD a contiguous
// chunk of 1376 tiles (~21 images), so halo + phase-4 re-reads hit local L2.

#define NPIX   87040
#define EPSV   1e-3f
#define WSUM   0.9999f      // 0.2989 + 0.587 + 0.114
#define TW     64
#define TH     16
#define RAD    6
#define LW     80           // loaded px per row: [tx0-8, tx0+72)
#define LH     28           // loaded rows: [ty0-6, ty0+22)
#define NG     (LH * 20)    // 560 groups of 4 px
#define NBLK   11008
#define NXCD   8
#define CHUNK  (NBLK / NXCD)   // 1376, exact

// 1D Gaussian taps G1[d+6] = exp(-d^2/18)/sqrt(18*pi), d = -6..6
__device__ __constant__ float G1[13] = {
    0.01799699f, 0.03315904f, 0.05467002f, 0.08065689f, 0.10648267f,
    0.12579441f, 0.13298076f, 0.12579441f, 0.10648267f, 0.08065689f,
    0.05467002f, 0.03315904f, 0.01799699f
};
// prefix sums PRE[i] = sum_{j<i} G1[j]
__device__ __constant__ float PRE[14] = {
    0.00000000f, 0.01799699f, 0.05115603f, 0.10582605f, 0.18648294f,
    0.29296561f, 0.41876002f, 0.55174078f, 0.67753519f, 0.78401786f,
    0.86467475f, 0.91934477f, 0.95250381f, 0.97050080f
};

__global__ __launch_bounds__(256)
void mslln_kernel(const float* __restrict__ x, float* __restrict__ out) {
    __shared__ float s_lum[LH][LW];     // 28x80 = 8.75 KB
    __shared__ float s_rc[LH][TW];      // 28x64 = 7 KB
    __shared__ float s_scale[TH][TW];   // 16x64 = 4 KB   (total 19.75 KB -> 8 blk/CU)

    // XCD-aware swizzle: physical block b lands on XCD b%8 (round-robin
    // dispatch); give XCD k the contiguous logical range [k*1376,(k+1)*1376).
    const int bphys = blockIdx.x;
    const int bid   = (bphys & (NXCD - 1)) * CHUNK + (bphys >> 3);
    const int t     = threadIdx.x;

    // block -> (level, image, tile); tiles are 64x16 outputs
    // L0: 256x256 -> 4x16=64 tiles *128 = 8192   [0,8192)
    // L1: 128x128 -> 2x8 =16 tiles *128 = 2048   [8192,10240)
    // L2:  64x64  -> 1x4 =4  tiles *128 =  512   [10240,10752)
    // L3:  32x32  -> 1x2 =2  tiles *128 =  256   [10752,11008)
    int img, tl, txlog, h, off;
    if (bid < 8192)       { img = bid >> 6;                 tl = bid & 63; txlog = 2; h = 256; off = 0;     }
    else if (bid < 10240) { int r = bid - 8192;  img = r >> 4; tl = r & 15; txlog = 1; h = 128; off = 65536; }
    else if (bid < 10752) { int r = bid - 10240; img = r >> 2; tl = r & 3;  txlog = 0; h = 64;  off = 81920; }
    else                  { int r = bid - 10752; img = r >> 1; tl = r & 1;  txlog = 0; h = 32;  off = 86016; }
    const int w   = h;
    const int tx0 = (tl & ((1 << txlog) - 1)) << 6;  // *64
    const int ty0 = (tl >> txlog) << 4;              // *16

    const float* __restrict__ xb = x   + (size_t)img * (NPIX * 3) + (size_t)off * 3;
    float*       __restrict__ ob = out + (size_t)img * (NPIX * 3) + (size_t)off * 3;

    // ---- Phase 1: vectorized load, lum -> LDS (4 px / thread-iter) ----
#pragma unroll
    for (int k = 0; k < 3; k++) {
        unsigned i = t + k * 256;
        if (i < NG) {
            int gr  = i / 20;
            int gc  = i - gr * 20;
            int gy  = ty0 + gr - RAD;
            int gx0 = tx0 + (gc << 2) - 8;   // float index 3*gx0 is 16B-aligned
            float4 f0 = {0,0,0,0}, f1 = {0,0,0,0}, f2 = {0,0,0,0};
            if (gy >= 0 && gy < h) {
                if (gx0 >= 0 && gx0 + 3 < w) {
                    const float4* p = (const float4*)(xb + ((size_t)gy * w + gx0) * 3);
                    f0 = p[0]; f1 = p[1]; f2 = p[2];
                } else {
                    float v[12];
#pragma unroll
                    for (int c = 0; c < 12; c++) v[c] = 0.f;
#pragma unroll
                    for (int c = 0; c < 4; c++) {
                        int gx = gx0 + c;
                        if (gx >= 0 && gx < w) {
                            const float* s = xb + ((size_t)gy * w + gx) * 3;
                            v[3*c] = s[0]; v[3*c+1] = s[1]; v[3*c+2] = s[2];
                        }
                    }
                    f0 = make_float4(v[0], v[1], v[2],  v[3]);
                    f1 = make_float4(v[4], v[5], v[6],  v[7]);
                    f2 = make_float4(v[8], v[9], v[10], v[11]);
                }
            }
            float l0 = 0.2989f*f0.x + 0.587f*f0.y + 0.114f*f0.z;
            float l1 = 0.2989f*f0.w + 0.587f*f1.x + 0.114f*f1.y;
            float l2 = 0.2989f*f1.z + 0.587f*f1.w + 0.114f*f2.x;
            float l3 = 0.2989f*f2.y + 0.587f*f2.z + 0.114f*f2.w;
            *(float4*)&s_lum[gr][gc << 2] = make_float4(l0, l1, l2, l3);
        }
    }
    __syncthreads();

    // ---- Phase 2: row conv, 28x64 = 1792 = 7*256 exact ----
    // s_lum[r][c] holds pixel gx = tx0 + c - 8; output col c taps indices c+2..c+14
#pragma unroll
    for (int k = 0; k < 7; k++) {
        int i = t + k * 256;
        int r = i >> 6, c = i & 63;
        float s = 0.f;
#pragma unroll
        for (int j = 0; j < 13; j++) s += s_lum[r][c + 2 + j] * G1[j];
        s_rc[r][c] = s;
    }
    __syncthreads();

    // ---- Phase 3: col conv + analytic dens -> per-pixel scale ----
#pragma unroll
    for (int k = 0; k < 4; k++) {
        int i  = t + k * 256;
        int ly = i >> 6, lx = i & 63;
        if (tx0 + lx < w) {                 // only false on L3 (w=32)
            float s = 0.f;
#pragma unroll
            for (int j = 0; j < 13; j++) s += s_rc[ly + j][lx] * G1[j];
            int gy = ty0 + ly, gx = tx0 + lx;
            int ylo = min(RAD, gy), yhi = min(RAD, h - 1 - gy);
            int xlo = min(RAD, gx), xhi = min(RAD, w - 1 - gx);
            float Sy = PRE[RAD + yhi + 1] - PRE[RAD - ylo];
            float Sx = PRE[RAD + xhi + 1] - PRE[RAD - xlo];
            float dens = WSUM * Sy * Sx;
            s_scale[ly][lx] = 1.0f / (s / dens + EPSV);
        }
    }
    __syncthreads();

    // ---- Phase 4: re-read RGB (L2 hit), scale, vectorized store ----
    {
        int gr  = t >> 4;            // 16 rows
        int gc  = t & 15;            // 16 groups of 4 px = 64 px
        int gx0 = tx0 + (gc << 2);
        if (gx0 < w) {               // only false on L3 (w=32)
            int gy = ty0 + gr;
            const float4* p = (const float4*)(xb + ((size_t)gy * w + gx0) * 3);
            float4 f0 = p[0], f1 = p[1], f2 = p[2];
            float4 sc = *(const float4*)&s_scale[gr][gc << 2];
            f0.x *= sc.x; f0.y *= sc.x; f0.z *= sc.x; f0.w *= sc.y;
            f1.x *= sc.y; f1.y *= sc.y; f1.z *= sc.z; f1.w *= sc.z;
            f2.x *= sc.z; f2.y *= sc.w; f2.z *= sc.w; f2.w *= sc.w;
            float4* q = (float4*)(ob + ((size_t)gy * w + gx0) * 3);
            q[0] = f0; q[1] = f1; q[2] = f2;
        }
    }
}

extern "C" void kernel_launch(void* const* d_in, const int* in_sizes, int n_in,
                              void* d_out, int out_size, void* d_ws, size_t ws_size,
                              hipStream_t stream) {
    const float* x = (const float*)d_in[0];
    float* out = (float*)d_out;
    mslln_kernel<<<NBLK, 256, 0, stream>>>(x, out);
}

// Round 3
// 243.949 us; speedup vs baseline: 1.0059x; 1.0059x over previous
//
#include <hip/hip_runtime.h>

// MultiscaleLLN: out = x / (gauss13x13(lum(x)) / dens + eps), 4 pyramid levels.
// Separable Gaussian; dens analytic via prefix sums.
// R4: XCD-aware block swizzle (kept — FETCH 194->115 MB).
// R5: latency/issue restructure:
//   - phase 2/3 convs use ds_read_b128 sliding windows (143 b32 -> ~23 b128
//     LDS reads per thread; LDS bytes 146->89 KB/block)
//   - phase-4 RGB is prefetched into VGPRs at the start of phase 2 (L1/L2-hot
//     lines; latency hides under row conv) -- no global read after barrier 3
//   - s_rc/s_scale padded to stride 68 (stride 64 aliases all rows to the
//     same banks); s_scale aliases s_lum (dead after phase 2) -> 17.0 KB LDS,
//     still 8 blocks/CU.
// R6: identical resubmit — R5 bench failed on container acquisition (infra),
//     kernel re-audited (alignment/bounds/aliasing) with no defect found.

#define NPIX   87040
#define EPSV   1e-3f
#define WSUM   0.9999f      // 0.2989 + 0.587 + 0.114
#define TW     64
#define TH     16
#define RAD    6
#define LW     80           // loaded px per row: [tx0-8, tx0+72)
#define LWP    84           // padded stride for s_lum (bank shift 20/row)
#define RCP    68           // padded stride for s_rc/s_scale (bank shift 4/row)
#define LH     28           // loaded rows: [ty0-6, ty0+22)
#define NG     (LH * 20)    // 560 groups of 4 px
#define NBLK   11008
#define NXCD   8
#define CHUNK  (NBLK / NXCD)   // 1376, exact

// 1D Gaussian taps G1[d+6] = exp(-d^2/18)/sqrt(18*pi), d = -6..6
__device__ __constant__ float G1[13] = {
    0.01799699f, 0.03315904f, 0.05467002f, 0.08065689f, 0.10648267f,
    0.12579441f, 0.13298076f, 0.12579441f, 0.10648267f, 0.08065689f,
    0.05467002f, 0.03315904f, 0.01799699f
};
// prefix sums PRE[i] = sum_{j<i} G1[j]
__device__ __constant__ float PRE[14] = {
    0.00000000f, 0.01799699f, 0.05115603f, 0.10582605f, 0.18648294f,
    0.29296561f, 0.41876002f, 0.55174078f, 0.67753519f, 0.78401786f,
    0.86467475f, 0.91934477f, 0.95250381f, 0.97050080f
};

__global__ __launch_bounds__(256)
void mslln_kernel(const float* __restrict__ x, float* __restrict__ out) {
    // s_scale aliases s_lum: s_lum dead after phase 2, barrier before phase 3.
    __shared__ float s_mem[LH * LWP];          // 28*84*4 = 9408 B
    __shared__ float s_rc[LH][RCP];            // 28*68*4 = 7616 B  (tot 17024)
    float (*s_lum)[LWP]   = (float(*)[LWP])s_mem;
    float (*s_scale)[RCP] = (float(*)[RCP])s_mem;

    // XCD-aware swizzle: physical block b lands on XCD b%8 (round-robin
    // dispatch); give XCD k the contiguous logical range [k*1376,(k+1)*1376).
    const int bphys = blockIdx.x;
    const int bid   = (bphys & (NXCD - 1)) * CHUNK + (bphys >> 3);
    const int t     = threadIdx.x;

    // block -> (level, image, tile); tiles are 64x16 outputs
    int img, tl, txlog, h, off;
    if (bid < 8192)       { img = bid >> 6;                 tl = bid & 63; txlog = 2; h = 256; off = 0;     }
    else if (bid < 10240) { int r = bid - 8192;  img = r >> 4; tl = r & 15; txlog = 1; h = 128; off = 65536; }
    else if (bid < 10752) { int r = bid - 10240; img = r >> 2; tl = r & 3;  txlog = 0; h = 64;  off = 81920; }
    else                  { int r = bid - 10752; img = r >> 1; tl = r & 1;  txlog = 0; h = 32;  off = 86016; }
    const int w   = h;
    const int tx0 = (tl & ((1 << txlog) - 1)) << 6;  // *64
    const int ty0 = (tl >> txlog) << 4;              // *16

    const float* __restrict__ xb = x   + (size_t)img * (NPIX * 3) + (size_t)off * 3;
    float*       __restrict__ ob = out + (size_t)img * (NPIX * 3) + (size_t)off * 3;

    // ---- Phase 1: vectorized load, lum -> LDS (4 px / thread-iter) ----
#pragma unroll
    for (int k = 0; k < 3; k++) {
        unsigned i = t + k * 256;
        if (i < NG) {
            int gr  = i / 20;
            int gc  = i - gr * 20;
            int gy  = ty0 + gr - RAD;
            int gx0 = tx0 + (gc << 2) - 8;   // float index 3*gx0 is 16B-aligned
            float4 f0 = {0,0,0,0}, f1 = {0,0,0,0}, f2 = {0,0,0,0};
            if (gy >= 0 && gy < h) {
                if (gx0 >= 0 && gx0 + 3 < w) {
                    const float4* p = (const float4*)(xb + ((size_t)gy * w + gx0) * 3);
                    f0 = p[0]; f1 = p[1]; f2 = p[2];
                } else {
                    float v[12];
#pragma unroll
                    for (int c = 0; c < 12; c++) v[c] = 0.f;
#pragma unroll
                    for (int c = 0; c < 4; c++) {
                        int gx = gx0 + c;
                        if (gx >= 0 && gx < w) {
                            const float* s = xb + ((size_t)gy * w + gx) * 3;
                            v[3*c] = s[0]; v[3*c+1] = s[1]; v[3*c+2] = s[2];
                        }
                    }
                    f0 = make_float4(v[0], v[1], v[2],  v[3]);
                    f1 = make_float4(v[4], v[5], v[6],  v[7]);
                    f2 = make_float4(v[8], v[9], v[10], v[11]);
                }
            }
            float l0 = 0.2989f*f0.x + 0.587f*f0.y + 0.114f*f0.z;
            float l1 = 0.2989f*f0.w + 0.587f*f1.x + 0.114f*f1.y;
            float l2 = 0.2989f*f1.z + 0.587f*f1.w + 0.114f*f2.x;
            float l3 = 0.2989f*f2.y + 0.587f*f2.z + 0.114f*f2.w;
            *(float4*)&s_lum[gr][gc << 2] = make_float4(l0, l1, l2, l3);
        }
    }
    __syncthreads();

    // ---- Phase 2a: prefetch phase-4 RGB into VGPRs (L1/L2-hot from phase 1;
    //      latency hides under the row conv below) ----
    const int p4_gr  = t >> 4;               // 16 rows
    const int p4_gc  = t & 15;               // 16 groups of 4 px
    const int p4_gx0 = tx0 + (p4_gc << 2);
    float4 f0p = {0,0,0,0}, f1p = {0,0,0,0}, f2p = {0,0,0,0};
    if (p4_gx0 < w) {                        // only false on L3 (w=32)
        const float4* p = (const float4*)(xb + ((size_t)(ty0 + p4_gr) * w + p4_gx0) * 3);
        f0p = p[0]; f1p = p[1]; f2p = p[2];
    }

    // ---- Phase 2b: row conv, 28 rows x 16 groups of 4 = 448 groups ----
    // s_lum[r][c] holds pixel gx = tx0 + c - 8; output col c taps cols c+2..c+14.
    // Sliding window: group c4 needs cols [c4+2, c4+18) -> load [c4, c4+20).
#pragma unroll
    for (int k = 0; k < 2; k++) {
        int gi = t + (k << 8);
        if (gi < 448) {
            int r  = gi >> 4;
            int c4 = (gi & 15) << 2;
            float a[20];
#pragma unroll
            for (int m = 0; m < 5; m++)
                *(float4*)&a[m << 2] = *(const float4*)&s_lum[r][c4 + (m << 2)];
            float s0 = 0.f, s1 = 0.f, s2 = 0.f, s3 = 0.f;
#pragma unroll
            for (int j = 0; j < 13; j++) {
                float gj = G1[j];
                s0 += a[2 + j] * gj;
                s1 += a[3 + j] * gj;
                s2 += a[4 + j] * gj;
                s3 += a[5 + j] * gj;
            }
            *(float4*)&s_rc[r][c4] = make_float4(s0, s1, s2, s3);
        }
    }
    __syncthreads();

    // ---- Phase 3: col conv (float4 rows) + analytic dens -> scale ----
    {
        int ly  = t >> 4;
        int lx4 = (t & 15) << 2;
        if (tx0 + lx4 < w) {                 // only false on L3 (w=32)
            float4 acc = {0.f, 0.f, 0.f, 0.f};
#pragma unroll
            for (int j = 0; j < 13; j++) {
                float4 v = *(const float4*)&s_rc[ly + j][lx4];
                float gj = G1[j];
                acc.x += v.x * gj; acc.y += v.y * gj;
                acc.z += v.z * gj; acc.w += v.w * gj;
            }
            int gy = ty0 + ly;
            int ylo = min(RAD, gy), yhi = min(RAD, h - 1 - gy);
            float Sy = PRE[RAD + yhi + 1] - PRE[RAD - ylo];
            float4 sc;
#pragma unroll
            for (int d = 0; d < 4; d++) {
                int gx = tx0 + lx4 + d;
                int xlo = min(RAD, gx), xhi = min(RAD, w - 1 - gx);
                float Sx = PRE[RAD + xhi + 1] - PRE[RAD - xlo];
                float dens = WSUM * Sy * Sx;
                float s = (d == 0) ? acc.x : (d == 1) ? acc.y : (d == 2) ? acc.z : acc.w;
                float r = dens / (s + EPSV * dens);   // == 1/(s/dens + eps)
                if (d == 0) sc.x = r; else if (d == 1) sc.y = r;
                else if (d == 2) sc.z = r; else sc.w = r;
            }
            *(float4*)&s_scale[ly][lx4] = sc;
        }
    }
    __syncthreads();

    // ---- Phase 4: scale retained RGB, vectorized store ----
    if (p4_gx0 < w) {
        float4 sc = *(const float4*)&s_scale[p4_gr][p4_gc << 2];
        f0p.x *= sc.x; f0p.y *= sc.x; f0p.z *= sc.x; f0p.w *= sc.y;
        f1p.x *= sc.y; f1p.y *= sc.y; f1p.z *= sc.z; f1p.w *= sc.z;
        f2p.x *= sc.z; f2p.y *= sc.w; f2p.z *= sc.w; f2p.w *= sc.w;
        float4* q = (float4*)(ob + ((size_t)(ty0 + p4_gr) * w + p4_gx0) * 3);
        q[0] = f0p; q[1] = f1p; q[2] = f2p;
    }
}

extern "C" void kernel_launch(void* const* d_in, const int* in_sizes, int n_in,
                              void* d_out, int out_size, void* d_ws, size_t ws_size,
                              hipStream_t stream) {
    const float* x = (const float*)d_in[0];
    float* out = (float*)d_out;
    mslln_kernel<<<NBLK, 256, 0, stream>>>(x, out);
}